// Round 1
// baseline (2248.590 us; speedup 1.0000x reference)
//
#include <hip/hip_runtime.h>
#include <cstddef>

constexpr int B = 4, S = 2048, E = 1024, H = 16, D = 64;
constexpr int M_ROWS = B * S;   // 8192

// ---------------------------------------------------------------------------
// GEMM: C[M,N] = A[M,K] @ W[N,K]^T + bias[N]
// MODE 0: write C row-major [M,N]
// MODE 1: scatter packed QKV output into q/k/v buffers laid out [B,H,S,D]
// 128x128 tile, BK=8, 256 threads, 8x8 micro-tile per thread.
// ---------------------------------------------------------------------------
template<int MODE>
__global__ __launch_bounds__(256)
void gemm_xwt(const float* __restrict__ A, const float* __restrict__ W,
              const float* __restrict__ bias, float* __restrict__ C,
              float* __restrict__ qd, float* __restrict__ kd, float* __restrict__ vd,
              int M, int N, int K)
{
    constexpr int BM = 128, BN = 128, BK = 8;
    __shared__ float As[BK][BM];
    __shared__ float Bs[BK][BN];
    const int t  = threadIdx.x;
    const int tx = t & 15, ty = t >> 4;
    const int m0 = blockIdx.y * BM;
    const int n0 = blockIdx.x * BN;

    float acc[8][8] = {};

    for (int k0 = 0; k0 < K; k0 += BK) {
        #pragma unroll
        for (int i = 0; i < 4; ++i) {
            int flat = i * 256 + t;
            int r = flat >> 3, c = flat & 7;
            As[c][r] = A[(size_t)(m0 + r) * K + (k0 + c)];
            Bs[c][r] = W[(size_t)(n0 + r) * K + (k0 + c)];
        }
        __syncthreads();
        #pragma unroll
        for (int kk = 0; kk < BK; ++kk) {
            float a[8], b[8];
            *(float4*)&a[0] = *(const float4*)&As[kk][ty * 8];
            *(float4*)&a[4] = *(const float4*)&As[kk][ty * 8 + 4];
            *(float4*)&b[0] = *(const float4*)&Bs[kk][tx * 8];
            *(float4*)&b[4] = *(const float4*)&Bs[kk][tx * 8 + 4];
            #pragma unroll
            for (int i = 0; i < 8; ++i)
                #pragma unroll
                for (int j = 0; j < 8; ++j)
                    acc[i][j] += a[i] * b[j];
        }
        __syncthreads();
    }

    if (MODE == 0) {
        #pragma unroll
        for (int i = 0; i < 8; ++i) {
            int row = m0 + ty * 8 + i;
            #pragma unroll
            for (int j = 0; j < 8; ++j) {
                int col = n0 + tx * 8 + j;
                C[(size_t)row * N + col] = acc[i][j] + bias[col];
            }
        }
    } else {
        const int which = n0 >> 10;                       // 0:q 1:k 2:v (uniform per block)
        float* dst = (which == 0) ? qd : ((which == 1) ? kd : vd);
        #pragma unroll
        for (int i = 0; i < 8; ++i) {
            int row = m0 + ty * 8 + i;
            int b_ = row >> 11;                           // row / S
            int s_ = row & (S - 1);
            #pragma unroll
            for (int j = 0; j < 8; ++j) {
                int col = n0 + tx * 8 + j;
                int e  = col & (E - 1);
                int h_ = e >> 6, d_ = e & 63;
                dst[(((size_t)(b_ * H + h_)) * S + s_) * D + d_] = acc[i][j] + bias[col];
            }
        }
    }
}

// ---------------------------------------------------------------------------
// Flash-style attention with additive rel-pos bias.
// One block = one (b,h) and a 64-row Q tile. 256 threads:
//   row = t>>2 (0..63), sub = t&3 (each row handled by 4 consecutive lanes,
//   each lane owns 16 of the 64 output columns).
// Online softmax; K tile stored transposed in LDS so inner loops read float4.
// ---------------------------------------------------------------------------
__global__ __launch_bounds__(256)
void attn_fwd(const float* __restrict__ Q, const float* __restrict__ K,
              const float* __restrict__ V, const float* __restrict__ rel,
              float* __restrict__ AO)
{
    constexpr int QT = 64, KT = 64, PAD = 68;   // PAD: float4-aligned, odd*4 banks
    __shared__ float Qs [QT][PAD];
    __shared__ float KsT[D ][PAD];   // [d][k-col]
    __shared__ float Vs [KT][PAD];   // [k-row][d]
    __shared__ float Ps [QT][PAD];   // probs

    const int t   = threadIdx.x;
    const int row = t >> 2, sub = t & 3;
    const int bh  = blockIdx.y;                 // 0..63
    const int q0  = blockIdx.x * QT;
    const int b_  = bh >> 4, h_ = bh & 15;
    const float scale = 0.125f;                 // 1/sqrt(64)

    #pragma unroll
    for (int i = 0; i < 16; ++i) {
        int flat = i * 256 + t;
        int r = flat >> 6, c = flat & 63;
        Qs[r][c] = Q[((size_t)bh * S + q0 + r) * D + c];
    }

    float m_run = -3.0e38f, l_run = 0.f;
    float o[16] = {};

    for (int k0 = 0; k0 < S; k0 += KT) {
        __syncthreads();   // prev iter's Vs/Ps reads done
        #pragma unroll
        for (int i = 0; i < 16; ++i) {
            int flat = i * 256 + t;
            int r = flat >> 6, c = flat & 63;
            float kv = K[((size_t)bh * S + k0 + r) * D + c];
            float vv = V[((size_t)bh * S + k0 + r) * D + c];
            KsT[c][r] = kv;
            Vs[r][c]  = vv;
        }
        __syncthreads();

        // scores: s[j] = dot(Q[row], K[k0+sub*16+j]) over D
        float s[16];
        #pragma unroll
        for (int j = 0; j < 16; ++j) s[j] = 0.f;
        #pragma unroll 8
        for (int d = 0; d < D; ++d) {
            float qd = Qs[row][d];
            float kv[16];
            const float* kr = &KsT[d][sub * 16];
            *(float4*)&kv[0]  = *(const float4*)&kr[0];
            *(float4*)&kv[4]  = *(const float4*)&kr[4];
            *(float4*)&kv[8]  = *(const float4*)&kr[8];
            *(float4*)&kv[12] = *(const float4*)&kr[12];
            #pragma unroll
            for (int j = 0; j < 16; ++j) s[j] += qd * kv[j];
        }

        const float* relrow = &rel[(size_t)(q0 + row) * S + k0 + sub * 16];
        #pragma unroll
        for (int j = 0; j < 16; ++j) s[j] = s[j] * scale + relrow[j];

        // row max across 16 local + 4 lanes of this row
        float ml = s[0];
        #pragma unroll
        for (int j = 1; j < 16; ++j) ml = fmaxf(ml, s[j]);
        ml = fmaxf(ml, __shfl_xor(ml, 1));
        ml = fmaxf(ml, __shfl_xor(ml, 2));
        const float mnew  = fmaxf(m_run, ml);
        const float alpha = __expf(m_run - mnew);

        float lsum = 0.f;
        #pragma unroll
        for (int j = 0; j < 16; ++j) { float p = __expf(s[j] - mnew); s[j] = p; lsum += p; }
        lsum += __shfl_xor(lsum, 1);
        lsum += __shfl_xor(lsum, 2);
        l_run = l_run * alpha + lsum;
        m_run = mnew;

        #pragma unroll
        for (int j = 0; j < 16; ++j) o[j] *= alpha;

        *(float4*)&Ps[row][sub * 16]      = *(const float4*)&s[0];
        *(float4*)&Ps[row][sub * 16 + 4]  = *(const float4*)&s[4];
        *(float4*)&Ps[row][sub * 16 + 8]  = *(const float4*)&s[8];
        *(float4*)&Ps[row][sub * 16 + 12] = *(const float4*)&s[12];
        __syncthreads();

        // O[row][c] += sum_k P[row][k] * V[k][c]   (c = sub*16 .. sub*16+15)
        #pragma unroll 8
        for (int kk = 0; kk < KT; ++kk) {
            float pk = Ps[row][kk];
            float vv[16];
            const float* vr = &Vs[kk][sub * 16];
            *(float4*)&vv[0]  = *(const float4*)&vr[0];
            *(float4*)&vv[4]  = *(const float4*)&vr[4];
            *(float4*)&vv[8]  = *(const float4*)&vr[8];
            *(float4*)&vv[12] = *(const float4*)&vr[12];
            #pragma unroll
            for (int j = 0; j < 16; ++j) o[j] += pk * vv[j];
        }
    }

    const float inv = 1.f / l_run;
    float* dst = &AO[((size_t)(b_ * S + q0 + row)) * E + h_ * D + sub * 16];
    #pragma unroll
    for (int j = 0; j < 16; ++j) dst[j] = o[j] * inv;
}

// ---------------------------------------------------------------------------
extern "C" void kernel_launch(void* const* d_in, const int* in_sizes, int n_in,
                              void* d_out, int out_size, void* d_ws, size_t ws_size,
                              hipStream_t stream)
{
    const float* x   = (const float*)d_in[0];   // [B,S,E]
    const float* w1  = (const float*)d_in[1];   // [3E,E]
    const float* b1  = (const float*)d_in[2];   // [3E]
    const float* w2  = (const float*)d_in[3];   // [E,E]
    const float* b2  = (const float*)d_in[4];   // [E]
    const float* rel = (const float*)d_in[5];   // [S,S]
    float* out = (float*)d_out;

    float* ws = (float*)d_ws;
    const size_t chunk = (size_t)B * H * S * D; // 8,388,608 floats = 32 MB
    float* qb = ws;
    float* kb = ws + chunk;
    float* vb = ws + 2 * chunk;
    float* ao = ws + 3 * chunk;                 // [B,S,E]

    // 1) packed QKV projection, scatter to [B,H,S,D]
    dim3 g1(3 * E / 128, M_ROWS / 128);
    gemm_xwt<1><<<g1, dim3(256), 0, stream>>>(x, w1, b1, nullptr, qb, kb, vb,
                                              M_ROWS, 3 * E, E);
    // 2) attention per (b,h), 64-row q tiles
    dim3 g2(S / 64, B * H);
    attn_fwd<<<g2, dim3(256), 0, stream>>>(qb, kb, vb, rel, ao);

    // 3) output projection -> d_out
    dim3 g3(E / 128, M_ROWS / 128);
    gemm_xwt<0><<<g3, dim3(256), 0, stream>>>(ao, w2, b2, out,
                                              nullptr, nullptr, nullptr,
                                              M_ROWS, E, E);
}

// Round 2
// 1086.394 us; speedup vs baseline: 2.0698x; 2.0698x over previous
//
#include <hip/hip_runtime.h>
#include <cstddef>
#include <cstdint>

constexpr int B = 4, S = 2048, E = 1024, H = 16, D = 64;
constexpr int M_ROWS = B * S;   // 8192

typedef __bf16 bf16x8 __attribute__((ext_vector_type(8)));
typedef float  f32x4  __attribute__((ext_vector_type(4)));

__device__ __forceinline__ unsigned short f2bf(float x) {
    union { float f; uint32_t u; } v; v.f = x;
    uint32_t r = v.u + 0x7fff + ((v.u >> 16) & 1);   // RNE
    return (unsigned short)(r >> 16);
}

// ---------------------------------------------------------------------------
// GEMM: C[M,N] = A[M,K] @ W[N,K]^T + bias[N]   (fp32)
// MODE 0: write C row-major [M,N] fp32
// MODE 1: scatter packed QKV: q,k -> bf16 [B,H,S,D]; v -> bf16 [B,H,D,S]
// ---------------------------------------------------------------------------
template<int MODE>
__global__ __launch_bounds__(256)
void gemm_xwt(const float* __restrict__ A, const float* __restrict__ W,
              const float* __restrict__ bias, float* __restrict__ C,
              unsigned short* __restrict__ qd, unsigned short* __restrict__ kd,
              unsigned short* __restrict__ vd, int M, int N, int K)
{
    constexpr int BM = 128, BN = 128, BK = 8;
    __shared__ float As[BK][BM];
    __shared__ float Bs[BK][BN];
    const int t  = threadIdx.x;
    const int tx = t & 15, ty = t >> 4;
    const int m0 = blockIdx.y * BM;
    const int n0 = blockIdx.x * BN;

    float acc[8][8] = {};

    for (int k0 = 0; k0 < K; k0 += BK) {
        #pragma unroll
        for (int i = 0; i < 4; ++i) {
            int flat = i * 256 + t;
            int r = flat >> 3, c = flat & 7;
            As[c][r] = A[(size_t)(m0 + r) * K + (k0 + c)];
            Bs[c][r] = W[(size_t)(n0 + r) * K + (k0 + c)];
        }
        __syncthreads();
        #pragma unroll
        for (int kk = 0; kk < BK; ++kk) {
            float a[8], b[8];
            *(float4*)&a[0] = *(const float4*)&As[kk][ty * 8];
            *(float4*)&a[4] = *(const float4*)&As[kk][ty * 8 + 4];
            *(float4*)&b[0] = *(const float4*)&Bs[kk][tx * 8];
            *(float4*)&b[4] = *(const float4*)&Bs[kk][tx * 8 + 4];
            #pragma unroll
            for (int i = 0; i < 8; ++i)
                #pragma unroll
                for (int j = 0; j < 8; ++j)
                    acc[i][j] += a[i] * b[j];
        }
        __syncthreads();
    }

    if (MODE == 0) {
        #pragma unroll
        for (int i = 0; i < 8; ++i) {
            int row = m0 + ty * 8 + i;
            #pragma unroll
            for (int j = 0; j < 8; ++j) {
                int col = n0 + tx * 8 + j;
                C[(size_t)row * N + col] = acc[i][j] + bias[col];
            }
        }
    } else {
        const int which = n0 >> 10;              // 0:q 1:k 2:v (uniform per block)
        if (which < 2) {
            unsigned short* dst = (which == 0) ? qd : kd;
            const int col0 = n0 + tx * 8;
            const int e0 = col0 & (E - 1);
            const int h_ = e0 >> 6, d0 = e0 & 63;   // 8 | 64 -> one head per chunk
            #pragma unroll
            for (int i = 0; i < 8; ++i) {
                int row = m0 + ty * 8 + i;
                int b_ = row >> 11, s_ = row & (S - 1);
                unsigned short tmp[8];
                #pragma unroll
                for (int j = 0; j < 8; ++j) tmp[j] = f2bf(acc[i][j] + bias[col0 + j]);
                *(int4*)&dst[(((size_t)(b_ * H + h_)) * S + s_) * D + d0] = *(const int4*)tmp;
            }
        } else {
            const int row0 = m0 + ty * 8;
            const int b_ = row0 >> 11, s0 = row0 & (S - 1);
            #pragma unroll
            for (int j = 0; j < 8; ++j) {
                int col = n0 + tx * 8 + j;
                int e = col & (E - 1);
                int h_ = e >> 6, d_ = e & 63;
                unsigned short tmp[8];
                #pragma unroll
                for (int i = 0; i < 8; ++i) tmp[i] = f2bf(acc[i][j] + bias[col]);
                *(int4*)&vd[(((size_t)(b_ * H + h_)) * D + d_) * S + s0] = *(const int4*)tmp;
            }
        }
    }
}

// ---------------------------------------------------------------------------
// MFMA flash attention. Block = 256 thr = 4 waves; one (b,h), 64 q-rows.
// Wave w owns q-rows [w*16, w*16+16). K-tile loop of 64 keys:
//   QK^T: mfma_f32_16x16x32_bf16, A=Q (regs), B=K (LDS, XOR-swizzled)
//   softmax fp32 in regs (row stats via 16-lane shfl_xor), P -> bf16 LDS
//   PV:   A=P (LDS), B=V via Vt tile [d][k] (LDS, XOR-swizzled)
// Swizzle: 16B chunk index ^= (row&7)  => <=2-way banks on all b128 reads.
// ---------------------------------------------------------------------------
__global__ __launch_bounds__(256)
void attn_mfma(const unsigned short* __restrict__ Qb,
               const unsigned short* __restrict__ Kb,
               const unsigned short* __restrict__ Vtb,
               const float* __restrict__ rel, float* __restrict__ AO)
{
    __shared__ unsigned short lds_k[4096];      // K  [64 k][64 d] swz
    __shared__ unsigned short lds_v[4096];      // Vt [64 d][64 k] swz
    __shared__ unsigned short lds_p[4][1024];   // per-wave P [16 q][64 k] swz

    const int t    = threadIdx.x;
    const int wid  = t >> 6, lane = t & 63;
    const int l16  = lane & 15, lg = lane >> 4;
    const int bh   = blockIdx.y;
    const int q0   = blockIdx.x * 64;
    const int b_   = bh >> 4, h_ = bh & 15;

    const size_t qkoff = (size_t)bh * S * D;
    const size_t vtoff = (size_t)bh * D * S;

    // Q A-frags: lane: q = q0 + wid*16 + l16, d = f*32 + lg*8 + j
    bf16x8 qf[2];
    {
        const unsigned short* qrow = Qb + qkoff + (size_t)(q0 + wid * 16 + l16) * D;
        qf[0] = *(const bf16x8*)(qrow + lg * 8);
        qf[1] = *(const bf16x8*)(qrow + 32 + lg * 8);
    }

    float m_run[4], l_run[4];
    f32x4 o[4];
    #pragma unroll
    for (int r = 0; r < 4; ++r) { m_run[r] = -3.0e38f; l_run[r] = 0.f; }
    #pragma unroll
    for (int dt = 0; dt < 4; ++dt) o[dt] = (f32x4){0.f, 0.f, 0.f, 0.f};

    for (int k0 = 0; k0 < S; k0 += 64) {
        __syncthreads();
        // stage K tile and Vt tile (each 512 x 16B chunks / 4 waves)
        #pragma unroll
        for (int i = 0; i < 2; ++i) {
            int c   = wid * 128 + i * 64 + lane;
            int row = c >> 3, cc = c & 7;
            int sc  = cc ^ (row & 7);          // linear LDS <- swizzled source chunk
            const unsigned short* gk = Kb  + qkoff + (size_t)(k0 + row) * D + sc * 8;
            *(int4*)&lds_k[c * 8] = *(const int4*)gk;
            const unsigned short* gv = Vtb + vtoff + (size_t)row * S + k0 + sc * 8;
            *(int4*)&lds_v[c * 8] = *(const int4*)gv;
        }
        __syncthreads();

        // ---- QK^T ----
        f32x4 acc[4];
        #pragma unroll
        for (int kt = 0; kt < 4; ++kt) acc[kt] = (f32x4){0.f, 0.f, 0.f, 0.f};
        #pragma unroll
        for (int f = 0; f < 2; ++f) {
            #pragma unroll
            for (int kt = 0; kt < 4; ++kt) {
                int key   = kt * 16 + l16;
                int chunk = (f * 4 + lg) ^ (key & 7);
                bf16x8 kf = *(const bf16x8*)&lds_k[key * 64 + chunk * 8];
                acc[kt] = __builtin_amdgcn_mfma_f32_16x16x32_bf16(qf[f], kf, acc[kt], 0, 0, 0);
            }
        }

        // ---- bias + online softmax (rows: q = lg*4 + r, spread over 16 lanes) ----
        const float* relbase = rel + (size_t)(q0 + wid * 16) * S + k0;
        float p[4][4], ml[4];
        #pragma unroll
        for (int r = 0; r < 4; ++r) ml[r] = -3.0e38f;
        #pragma unroll
        for (int kt = 0; kt < 4; ++kt)
            #pragma unroll
            for (int r = 0; r < 4; ++r) {
                float sv = acc[kt][r] * 0.125f
                         + relbase[(size_t)(lg * 4 + r) * S + kt * 16 + l16];
                p[kt][r] = sv;
                ml[r] = fmaxf(ml[r], sv);
            }
        #pragma unroll
        for (int r = 0; r < 4; ++r) {
            float v = ml[r];
            v = fmaxf(v, __shfl_xor(v, 1));
            v = fmaxf(v, __shfl_xor(v, 2));
            v = fmaxf(v, __shfl_xor(v, 4));
            v = fmaxf(v, __shfl_xor(v, 8));
            ml[r] = v;
        }
        float alpha[4], lsum[4];
        #pragma unroll
        for (int r = 0; r < 4; ++r) {
            float mnew = fmaxf(m_run[r], ml[r]);
            alpha[r] = __expf(m_run[r] - mnew);
            m_run[r] = mnew;
            lsum[r] = 0.f;
        }
        #pragma unroll
        for (int kt = 0; kt < 4; ++kt)
            #pragma unroll
            for (int r = 0; r < 4; ++r) {
                float e = __expf(p[kt][r] - m_run[r]);
                p[kt][r] = e;
                lsum[r] += e;
            }
        #pragma unroll
        for (int r = 0; r < 4; ++r) {
            float v = lsum[r];
            v += __shfl_xor(v, 1);
            v += __shfl_xor(v, 2);
            v += __shfl_xor(v, 4);
            v += __shfl_xor(v, 8);
            l_run[r] = l_run[r] * alpha[r] + v;
        }

        // P -> bf16 LDS (per-wave region, swizzled)
        unsigned short* pw = &lds_p[wid][0];
        #pragma unroll
        for (int kt = 0; kt < 4; ++kt)
            #pragma unroll
            for (int r = 0; r < 4; ++r) {
                int qr = lg * 4 + r;
                int k  = kt * 16 + l16;
                pw[qr * 64 + (((k >> 3) ^ (qr & 7)) << 3) + (k & 7)] = f2bf(p[kt][r]);
            }

        // rescale O
        #pragma unroll
        for (int dt = 0; dt < 4; ++dt)
            #pragma unroll
            for (int r = 0; r < 4; ++r)
                o[dt][r] *= alpha[r];

        // ---- PV ----
        #pragma unroll
        for (int f = 0; f < 2; ++f) {
            int pchunk = (f * 4 + lg) ^ (l16 & 7);
            bf16x8 pf = *(const bf16x8*)&pw[l16 * 64 + pchunk * 8];
            #pragma unroll
            for (int dt = 0; dt < 4; ++dt) {
                int d      = dt * 16 + l16;
                int vchunk = (f * 4 + lg) ^ (d & 7);
                bf16x8 vf  = *(const bf16x8*)&lds_v[d * 64 + vchunk * 8];
                o[dt] = __builtin_amdgcn_mfma_f32_16x16x32_bf16(pf, vf, o[dt], 0, 0, 0);
            }
        }
    }

    // epilogue: ao[b, s, h*64 + d] fp32
    #pragma unroll
    for (int r = 0; r < 4; ++r) {
        float inv = 1.f / l_run[r];
        int qr = q0 + wid * 16 + lg * 4 + r;
        float* dst = AO + ((size_t)b_ * S + qr) * E + h_ * 64;
        #pragma unroll
        for (int dt = 0; dt < 4; ++dt)
            dst[dt * 16 + l16] = o[dt][r] * inv;
    }
}

// ---------------------------------------------------------------------------
extern "C" void kernel_launch(void* const* d_in, const int* in_sizes, int n_in,
                              void* d_out, int out_size, void* d_ws, size_t ws_size,
                              hipStream_t stream)
{
    const float* x   = (const float*)d_in[0];
    const float* w1  = (const float*)d_in[1];
    const float* b1  = (const float*)d_in[2];
    const float* w2  = (const float*)d_in[3];
    const float* b2  = (const float*)d_in[4];
    const float* rel = (const float*)d_in[5];
    float* out = (float*)d_out;

    const size_t chunk = (size_t)B * H * S * D;      // 8,388,608 elements
    unsigned short* qb = (unsigned short*)d_ws;      // bf16 [B,H,S,D]
    unsigned short* kb = qb + chunk;                 // bf16 [B,H,S,D]
    unsigned short* vb = kb + chunk;                 // bf16 [B,H,D,S] (transposed)
    float* ao = (float*)(vb + chunk);                // fp32 [B,S,E]

    dim3 g1(3 * E / 128, M_ROWS / 128);
    gemm_xwt<1><<<g1, dim3(256), 0, stream>>>(x, w1, b1, nullptr, qb, kb, vb,
                                              M_ROWS, 3 * E, E);

    dim3 g2(S / 64, B * H);
    attn_mfma<<<g2, dim3(256), 0, stream>>>(qb, kb, vb, rel, ao);

    dim3 g3(E / 128, M_ROWS / 128);
    gemm_xwt<0><<<g3, dim3(256), 0, stream>>>(ao, w2, b2, out,
                                              nullptr, nullptr, nullptr,
                                              M_ROWS, E, E);
}

// Round 4
// 851.867 us; speedup vs baseline: 2.6396x; 1.2753x over previous
//
#include <hip/hip_runtime.h>
#include <cstddef>
#include <cstdint>

constexpr int B = 4, S = 2048, E = 1024, H = 16, D = 64;
constexpr int M_ROWS = B * S;   // 8192

typedef __bf16 bf16x8 __attribute__((ext_vector_type(8)));
typedef float  f32x4  __attribute__((ext_vector_type(4)));

__device__ __forceinline__ unsigned short f2bf(float x) {
    union { float f; uint32_t u; } v; v.f = x;
    uint32_t r = v.u + 0x7fff + ((v.u >> 16) & 1);   // RNE
    return (unsigned short)(r >> 16);
}
__device__ __forceinline__ float bf2f(unsigned short h) {
    union { uint32_t u; float f; } v; v.u = (uint32_t)h << 16; return v.f;
}

// ---------------------------------------------------------------------------
// Split fp32 -> (hi, lo) bf16 for x (4096 blks), w1 (1536 blks), w2 (512 blks).
// ---------------------------------------------------------------------------
__global__ __launch_bounds__(256)
void cvt3(const float* __restrict__ x,  unsigned short* __restrict__ xhi,  unsigned short* __restrict__ xlo,
          const float* __restrict__ w1, unsigned short* __restrict__ w1hi, unsigned short* __restrict__ w1lo,
          const float* __restrict__ w2, unsigned short* __restrict__ w2hi, unsigned short* __restrict__ w2lo)
{
    const int bid = blockIdx.x;
    const float* s; unsigned short *ph, *pl; size_t idx;
    if (bid < 4096)      { s = x;  ph = xhi;  pl = xlo;  idx = (size_t)bid * 256 + threadIdx.x; }
    else if (bid < 5632) { s = w1; ph = w1hi; pl = w1lo; idx = (size_t)(bid - 4096) * 256 + threadIdx.x; }
    else                 { s = w2; ph = w2hi; pl = w2lo; idx = (size_t)(bid - 5632) * 256 + threadIdx.x; }
    const float4* s4 = (const float4*)s;
    float4 v0 = s4[idx * 2], v1 = s4[idx * 2 + 1];
    float f[8] = { v0.x, v0.y, v0.z, v0.w, v1.x, v1.y, v1.z, v1.w };
    unsigned short hh[8], ll[8];
    #pragma unroll
    for (int j = 0; j < 8; ++j) {
        hh[j] = f2bf(f[j]);
        ll[j] = f2bf(f[j] - bf2f(hh[j]));
    }
    ((int4*)ph)[idx] = *(const int4*)hh;
    ((int4*)pl)[idx] = *(const int4*)ll;
}

// ---------------------------------------------------------------------------
// Split-bf16 MFMA GEMM: C[M,N] = (Ahi+Alo)[M,K] @ (Whi+Wlo)[N,K]^T + bias
//   via Ahi*Whi + Ahi*Wlo + Alo*Whi (fp32 accum).
// 128x128 tile, BK=32, 4 waves (2x2 of 64x64).
// Staging: global->reg (issued BEFORE barrier, latency hidden) -> ds_write_b128
//   (the race-safe pattern; global_load_lds diverged under graph replay in R3).
// Source-side XOR chunk swizzle (chunk ^= (row>>1)&3) -> conflict-free b128 reads.
// MODE 0: C fp32 [M,N] + bias
// MODE 1: QKV scatter: q,k -> bf16 [B,H,S,D]; v -> bf16 [B,H,D,S]
// ---------------------------------------------------------------------------
template<int MODE>
__global__ __launch_bounds__(256)
void gemm_mfma(const unsigned short* __restrict__ Ahi, const unsigned short* __restrict__ Alo,
               const unsigned short* __restrict__ Whi, const unsigned short* __restrict__ Wlo,
               const float* __restrict__ bias, float* __restrict__ C,
               unsigned short* __restrict__ qd, unsigned short* __restrict__ kd,
               unsigned short* __restrict__ vd, int M, int N, int K)
{
    __shared__ __align__(16) unsigned short lds4[4][128 * 32]; // Ahi, Alo, Whi, Wlo

    const int t    = threadIdx.x;
    const int wid  = t >> 6, lane = t & 63;
    const int l16  = lane & 15, lg = lane >> 4;
    const int wr   = wid >> 1, wc = wid & 1;
    const int m0   = blockIdx.y * 128;
    const int n0   = blockIdx.x * 128;

    // this thread's two staged chunks per array: c = half*256 + t
    int srow[2], soff[2];
    #pragma unroll
    for (int half = 0; half < 2; ++half) {
        int c = half * 256 + t;
        int row = c >> 2, cc = c & 3;
        int scc = cc ^ ((row >> 1) & 3);     // pre-swizzled source chunk
        srow[half] = row;
        soff[half] = scc * 8;
    }

    f32x4 acc[4][4];
    #pragma unroll
    for (int mi = 0; mi < 4; ++mi)
        #pragma unroll
        for (int ni = 0; ni < 4; ++ni) acc[mi][ni] = (f32x4){0.f, 0.f, 0.f, 0.f};

    for (int k0 = 0; k0 < K; k0 += 32) {
        const unsigned short* gsrc[4] = {
            Ahi + (size_t)m0 * K + k0, Alo + (size_t)m0 * K + k0,
            Whi + (size_t)n0 * K + k0, Wlo + (size_t)n0 * K + k0 };

        // issue all global loads first (overlap with barrier wait / other waves)
        int4 stg[8];
        #pragma unroll
        for (int arr = 0; arr < 4; ++arr)
            #pragma unroll
            for (int half = 0; half < 2; ++half)
                stg[arr * 2 + half] =
                    *(const int4*)(gsrc[arr] + (size_t)srow[half] * K + soff[half]);

        __syncthreads();    // previous iteration's LDS reads complete
        #pragma unroll
        for (int arr = 0; arr < 4; ++arr)
            #pragma unroll
            for (int half = 0; half < 2; ++half) {
                int c = half * 256 + t;
                *(int4*)&lds4[arr][c * 8] = stg[arr * 2 + half];
            }
        __syncthreads();

        bf16x8 ahi[4], alo[4], bhi[4], blo[4];
        #pragma unroll
        for (int mi = 0; mi < 4; ++mi) {
            int arow = wr * 64 + mi * 16 + l16;
            int co   = ((lg ^ ((arow >> 1) & 3)) << 3);
            ahi[mi] = *(const bf16x8*)&lds4[0][arow * 32 + co];
            alo[mi] = *(const bf16x8*)&lds4[1][arow * 32 + co];
        }
        #pragma unroll
        for (int ni = 0; ni < 4; ++ni) {
            int brow = wc * 64 + ni * 16 + l16;
            int co   = ((lg ^ ((brow >> 1) & 3)) << 3);
            bhi[ni] = *(const bf16x8*)&lds4[2][brow * 32 + co];
            blo[ni] = *(const bf16x8*)&lds4[3][brow * 32 + co];
        }
        #pragma unroll
        for (int mi = 0; mi < 4; ++mi)
            #pragma unroll
            for (int ni = 0; ni < 4; ++ni) {
                acc[mi][ni] = __builtin_amdgcn_mfma_f32_16x16x32_bf16(ahi[mi], bhi[ni], acc[mi][ni], 0, 0, 0);
                acc[mi][ni] = __builtin_amdgcn_mfma_f32_16x16x32_bf16(ahi[mi], blo[ni], acc[mi][ni], 0, 0, 0);
                acc[mi][ni] = __builtin_amdgcn_mfma_f32_16x16x32_bf16(alo[mi], bhi[ni], acc[mi][ni], 0, 0, 0);
            }
        // no trailing barrier: next iteration's pre-store barrier protects reads
    }

    const int colblk = n0 + wc * 64;
    if constexpr (MODE == 0) {
        #pragma unroll
        for (int mi = 0; mi < 4; ++mi)
            #pragma unroll
            for (int r = 0; r < 4; ++r) {
                int row = m0 + wr * 64 + mi * 16 + lg * 4 + r;
                #pragma unroll
                for (int ni = 0; ni < 4; ++ni) {
                    int col = colblk + ni * 16 + l16;
                    C[(size_t)row * N + col] = acc[mi][ni][r] + bias[col];
                }
            }
    } else {
        const int which = colblk >> 10;            // 0:q 1:k 2:v
        if (which < 2) {
            unsigned short* dst = (which == 0) ? qd : kd;
            #pragma unroll
            for (int mi = 0; mi < 4; ++mi)
                #pragma unroll
                for (int r = 0; r < 4; ++r) {
                    int row = m0 + wr * 64 + mi * 16 + lg * 4 + r;
                    int b_ = row >> 11, s_ = row & (S - 1);
                    #pragma unroll
                    for (int ni = 0; ni < 4; ++ni) {
                        int col = colblk + ni * 16 + l16;
                        int e = col & (E - 1);
                        int h_ = e >> 6, d_ = e & 63;
                        dst[(((size_t)(b_ * H + h_)) * S + s_) * D + d_] =
                            f2bf(acc[mi][ni][r] + bias[col]);
                    }
                }
        } else {
            #pragma unroll
            for (int mi = 0; mi < 4; ++mi) {
                int row0 = m0 + wr * 64 + mi * 16 + lg * 4;
                int b_ = row0 >> 11, s_ = row0 & (S - 1);
                #pragma unroll
                for (int ni = 0; ni < 4; ++ni) {
                    int col = colblk + ni * 16 + l16;
                    int e = col & (E - 1);
                    int h_ = e >> 6, d_ = e & 63;
                    float bv = bias[col];
                    unsigned short tmp[4];
                    #pragma unroll
                    for (int r = 0; r < 4; ++r) tmp[r] = f2bf(acc[mi][ni][r] + bv);
                    *(uint2*)&vd[(((size_t)(b_ * H + h_)) * D + d_) * S + s_] = *(const uint2*)tmp;
                }
            }
        }
    }
}

// ---------------------------------------------------------------------------
// MFMA flash attention — epilogue writes hi/lo bf16 for the out-proj GEMM.
// ---------------------------------------------------------------------------
__global__ __launch_bounds__(256)
void attn_mfma(const unsigned short* __restrict__ Qb,
               const unsigned short* __restrict__ Kb,
               const unsigned short* __restrict__ Vtb,
               const float* __restrict__ rel,
               unsigned short* __restrict__ AOhi, unsigned short* __restrict__ AOlo)
{
    __shared__ unsigned short lds_k[4096];      // K  [64 k][64 d] swz
    __shared__ unsigned short lds_v[4096];      // Vt [64 d][64 k] swz
    __shared__ unsigned short lds_p[4][1024];   // per-wave P [16 q][64 k] swz

    const int t    = threadIdx.x;
    const int wid  = t >> 6, lane = t & 63;
    const int l16  = lane & 15, lg = lane >> 4;
    const int bh   = blockIdx.y;
    const int q0   = blockIdx.x * 64;
    const int b_   = bh >> 4, h_ = bh & 15;

    const size_t qkoff = (size_t)bh * S * D;
    const size_t vtoff = (size_t)bh * D * S;

    bf16x8 qf[2];
    {
        const unsigned short* qrow = Qb + qkoff + (size_t)(q0 + wid * 16 + l16) * D;
        qf[0] = *(const bf16x8*)(qrow + lg * 8);
        qf[1] = *(const bf16x8*)(qrow + 32 + lg * 8);
    }

    float m_run[4], l_run[4];
    f32x4 o[4];
    #pragma unroll
    for (int r = 0; r < 4; ++r) { m_run[r] = -3.0e38f; l_run[r] = 0.f; }
    #pragma unroll
    for (int dt = 0; dt < 4; ++dt) o[dt] = (f32x4){0.f, 0.f, 0.f, 0.f};

    for (int k0 = 0; k0 < S; k0 += 64) {
        __syncthreads();
        #pragma unroll
        for (int i = 0; i < 2; ++i) {
            int c   = wid * 128 + i * 64 + lane;
            int row = c >> 3, cc = c & 7;
            int sc  = cc ^ (row & 7);
            const unsigned short* gk = Kb  + qkoff + (size_t)(k0 + row) * D + sc * 8;
            *(int4*)&lds_k[c * 8] = *(const int4*)gk;
            const unsigned short* gv = Vtb + vtoff + (size_t)row * S + k0 + sc * 8;
            *(int4*)&lds_v[c * 8] = *(const int4*)gv;
        }
        __syncthreads();

        f32x4 acc[4];
        #pragma unroll
        for (int kt = 0; kt < 4; ++kt) acc[kt] = (f32x4){0.f, 0.f, 0.f, 0.f};
        #pragma unroll
        for (int f = 0; f < 2; ++f) {
            #pragma unroll
            for (int kt = 0; kt < 4; ++kt) {
                int key   = kt * 16 + l16;
                int chunk = (f * 4 + lg) ^ (key & 7);
                bf16x8 kf = *(const bf16x8*)&lds_k[key * 64 + chunk * 8];
                acc[kt] = __builtin_amdgcn_mfma_f32_16x16x32_bf16(qf[f], kf, acc[kt], 0, 0, 0);
            }
        }

        const float* relbase = rel + (size_t)(q0 + wid * 16) * S + k0;
        float p[4][4], ml[4];
        #pragma unroll
        for (int r = 0; r < 4; ++r) ml[r] = -3.0e38f;
        #pragma unroll
        for (int kt = 0; kt < 4; ++kt)
            #pragma unroll
            for (int r = 0; r < 4; ++r) {
                float sv = acc[kt][r] * 0.125f
                         + relbase[(size_t)(lg * 4 + r) * S + kt * 16 + l16];
                p[kt][r] = sv;
                ml[r] = fmaxf(ml[r], sv);
            }
        #pragma unroll
        for (int r = 0; r < 4; ++r) {
            float v = ml[r];
            v = fmaxf(v, __shfl_xor(v, 1));
            v = fmaxf(v, __shfl_xor(v, 2));
            v = fmaxf(v, __shfl_xor(v, 4));
            v = fmaxf(v, __shfl_xor(v, 8));
            ml[r] = v;
        }
        float alpha[4];
        #pragma unroll
        for (int r = 0; r < 4; ++r) {
            float mnew = fmaxf(m_run[r], ml[r]);
            alpha[r] = __expf(m_run[r] - mnew);
            m_run[r] = mnew;
        }
        float lsum[4] = {0.f, 0.f, 0.f, 0.f};
        #pragma unroll
        for (int kt = 0; kt < 4; ++kt)
            #pragma unroll
            for (int r = 0; r < 4; ++r) {
                float e = __expf(p[kt][r] - m_run[r]);
                p[kt][r] = e;
                lsum[r] += e;
            }
        #pragma unroll
        for (int r = 0; r < 4; ++r) {
            float v = lsum[r];
            v += __shfl_xor(v, 1);
            v += __shfl_xor(v, 2);
            v += __shfl_xor(v, 4);
            v += __shfl_xor(v, 8);
            l_run[r] = l_run[r] * alpha[r] + v;
        }

        unsigned short* pw = &lds_p[wid][0];
        #pragma unroll
        for (int kt = 0; kt < 4; ++kt)
            #pragma unroll
            for (int r = 0; r < 4; ++r) {
                int qr = lg * 4 + r;
                int k  = kt * 16 + l16;
                pw[qr * 64 + (((k >> 3) ^ (qr & 7)) << 3) + (k & 7)] = f2bf(p[kt][r]);
            }

        #pragma unroll
        for (int dt = 0; dt < 4; ++dt)
            #pragma unroll
            for (int r = 0; r < 4; ++r)
                o[dt][r] *= alpha[r];

        #pragma unroll
        for (int f = 0; f < 2; ++f) {
            int pchunk = (f * 4 + lg) ^ (l16 & 7);
            bf16x8 pf = *(const bf16x8*)&pw[l16 * 64 + pchunk * 8];
            #pragma unroll
            for (int dt = 0; dt < 4; ++dt) {
                int d      = dt * 16 + l16;
                int vchunk = (f * 4 + lg) ^ (d & 7);
                bf16x8 vf  = *(const bf16x8*)&lds_v[d * 64 + vchunk * 8];
                o[dt] = __builtin_amdgcn_mfma_f32_16x16x32_bf16(pf, vf, o[dt], 0, 0, 0);
            }
        }
    }

    #pragma unroll
    for (int r = 0; r < 4; ++r) {
        float inv = 1.f / l_run[r];
        int qr = q0 + wid * 16 + lg * 4 + r;
        size_t base = ((size_t)b_ * S + qr) * E + h_ * 64;
        #pragma unroll
        for (int dt = 0; dt < 4; ++dt) {
            float v = o[dt][r] * inv;
            unsigned short hh = f2bf(v);
            AOhi[base + dt * 16 + l16] = hh;
            AOlo[base + dt * 16 + l16] = f2bf(v - bf2f(hh));
        }
    }
}

// ---------------------------------------------------------------------------
extern "C" void kernel_launch(void* const* d_in, const int* in_sizes, int n_in,
                              void* d_out, int out_size, void* d_ws, size_t ws_size,
                              hipStream_t stream)
{
    const float* x   = (const float*)d_in[0];
    const float* w1  = (const float*)d_in[1];
    const float* b1  = (const float*)d_in[2];
    const float* w2  = (const float*)d_in[3];
    const float* b2  = (const float*)d_in[4];
    const float* rel = (const float*)d_in[5];
    float* out = (float*)d_out;

    // workspace (all bf16/ushort), 128 MiB total
    unsigned short* p = (unsigned short*)d_ws;
    const size_t nx = (size_t)M_ROWS * E;        // 8,388,608
    const size_t n1 = (size_t)3 * E * E;         // 3,145,728
    const size_t n2 = (size_t)E * E;             // 1,048,576
    unsigned short* xhi  = p;            p += nx;
    unsigned short* xlo  = p;            p += nx;
    unsigned short* w1hi = p;            p += n1;
    unsigned short* w1lo = p;            p += n1;
    unsigned short* w2hi = p;            p += n2;
    unsigned short* w2lo = p;            p += n2;
    unsigned short* qb   = p;            p += nx; // [B,H,S,D]
    unsigned short* kb   = p;            p += nx; // [B,H,S,D]
    unsigned short* vb   = p;            p += nx; // [B,H,D,S]
    unsigned short* aohi = p;            p += nx; // [B,S,E]
    unsigned short* aolo = p;

    cvt3<<<dim3(6144), dim3(256), 0, stream>>>(x, xhi, xlo, w1, w1hi, w1lo, w2, w2hi, w2lo);

    dim3 g1(3 * E / 128, M_ROWS / 128);
    gemm_mfma<1><<<g1, dim3(256), 0, stream>>>(xhi, xlo, w1hi, w1lo, b1, nullptr,
                                               qb, kb, vb, M_ROWS, 3 * E, E);

    dim3 g2(S / 64, B * H);
    attn_mfma<<<g2, dim3(256), 0, stream>>>(qb, kb, vb, rel, aohi, aolo);

    dim3 g3(E / 128, M_ROWS / 128);
    gemm_mfma<0><<<g3, dim3(256), 0, stream>>>(aohi, aolo, w2hi, w2lo, b2, out,
                                               nullptr, nullptr, nullptr, M_ROWS, E, E);
}